// Round 11
// baseline (156.859 us; speedup 1.0000x reference)
//
#include <hip/hip_runtime.h>
#include <cmath>

#define BB   512
#define NSV  128
#define NTRK 512
#define KK   8
#define HH   16
#define TPB  1024          // 256 tracks x 4 scan segments
#define TRB  256           // tracks per block (half a batch)
#define SEGN 32            // SVs per segment
#define RSTR 20            // global row stride: [16 feats][0.5*||sv||^2][pad]
#define PSTR 20            // padded proj stride in LDS
#define TSTR 18            // tfS stride (8B-aligned rows, stride-2 banks = free)
#define KBS  25            // kbuf stride: 3 lists x 8 + 1 pad

typedef float vf2 __attribute__((ext_vector_type(2)));

__device__ __forceinline__ float elu_f(float x) {
    return x > 0.0f ? x : expm1f(x);
}
__device__ __forceinline__ unsigned umin_u(unsigned a, unsigned b) { return a < b ? a : b; }
__device__ __forceinline__ unsigned umax_u(unsigned a, unsigned b) { return a > b ? a : b; }
__device__ __forceinline__ unsigned med3u(unsigned a, unsigned b, unsigned c) {
    unsigned d;
    asm("v_med3_u32 %0, %1, %2, %3" : "=v"(d) : "v"(a), "v"(b), "v"(c));
    return d;
}
__device__ __forceinline__ void ceu(unsigned& a, unsigned& b) {
    unsigned lo = umin_u(a, b), hi = umax_u(a, b);
    a = lo; b = hi;
}
// a, b ascending sorted-8 -> a = ascending 8 smallest of union (exact)
__device__ __forceinline__ void merge8(unsigned* a, const unsigned* b) {
    unsigned s[8];
    #pragma unroll
    for (int i = 0; i < 8; ++i) s[i] = umin_u(a[i], b[7 - i]);   // bitonic
    #pragma unroll
    for (int i = 0; i < 4; ++i) ceu(s[i], s[i + 4]);
    ceu(s[0], s[2]); ceu(s[1], s[3]); ceu(s[4], s[6]); ceu(s[5], s[7]);
    ceu(s[0], s[1]); ceu(s[2], s[3]); ceu(s[4], s[5]); ceu(s[6], s[7]);
    #pragma unroll
    for (int i = 0; i < 8; ++i) a[i] = s[i];
}

// One block = 256 tracks of batch (blk>>1), half (blk&1).
// Thread (tl = tid&255, seg = tid>>8): scans SVs [seg*32, seg*32+32).
// Track MLP computed ONCE (threads 256..511) -> LDS; segs read it back.
// Rows round-trip via global ws (scalar-load path, L2-hot, both blocks write
// identical values - benign). Cross-block pooling via atomic + counter.
__global__ __launch_bounds__(TPB, 8) void fused_all(
    const float* __restrict__ x_sv, const float* __restrict__ x_trk,
    const float* __restrict__ W1s, const float* __restrict__ b1s,
    const float* __restrict__ W2s, const float* __restrict__ b2s,
    const float* __restrict__ W1t, const float* __restrict__ b1t,
    const float* __restrict__ W2t, const float* __restrict__ b2t,
    const float* __restrict__ We,  const float* __restrict__ be,
    const float* __restrict__ Wo,  const float* __restrict__ bo,
    float* __restrict__ svw,             // ws rows, write alias
    const float* __restrict__ svr,       // ws rows, read alias (scalar loads)
    float* __restrict__ pool_g, unsigned* __restrict__ cnt_g,
    float* __restrict__ out)
{
    __shared__ float    proj[NSV][PSTR];       // 10.2 KB
    __shared__ float    tfS[TRB][TSTR];        // 18.4 KB: tf[16], htsq
    __shared__ unsigned kbufS[TRB][KBS];       // 25.6 KB: lists of segs 1..3
    __shared__ float    ucS[HH + 1];
    __shared__ float    sred[4];

    const int blk = blockIdx.x;
    const int b   = blk >> 1, half = blk & 1;
    const int tid = threadIdx.x;
    const int tl  = tid & (TRB - 1);
    const int seg = __builtin_amdgcn_readfirstlane(tid >> 8);   // 0..3, wave-uniform

    // ---- phase A: SV MLP -> global rows + LDS proj (tid<128); u/c0 ----
    if (tid < NSV) {
        const float* xp = x_sv + (size_t)(b * NSV + tid) * 2;
        float x0 = xp[0], x1 = xp[1];
        float hb[HH];
        #pragma unroll
        for (int h = 0; h < HH; ++h)
            hb[h] = elu_f(x0 * W1s[h] + x1 * W1s[HH + h] + b1s[h]);
        float o[HH], sq = 0.0f;
        #pragma unroll
        for (int h2 = 0; h2 < HH; ++h2) {
            float a = b2s[h2];
            #pragma unroll
            for (int h = 0; h < HH; ++h) a += hb[h] * W2s[h * HH + h2];
            o[h2] = a;
            sq += a * a;
        }
        float* dst = svw + (size_t)(b * NSV + tid) * RSTR;
        #pragma unroll
        for (int h4 = 0; h4 < 4; ++h4)
            *(float4*)&dst[h4 * 4] = make_float4(o[h4*4], o[h4*4+1], o[h4*4+2], o[h4*4+3]);
        dst[HH] = 0.5f * sq;
        #pragma unroll
        for (int h = 0; h < HH; ++h) {
            float a = 0.0f;
            #pragma unroll
            for (int j = 0; j < HH; ++j) a += o[j] * We[(HH + j) * HH + h];
            proj[tid][h] = a;
        }
    } else if (tid < NSV + HH) {
        int j = tid - NSV;
        float a = 0.0f;
        #pragma unroll
        for (int h = 0; h < HH; ++h)
            a += (We[j * HH + h] - We[(HH + j) * HH + h]) * Wo[h];
        ucS[j] = a;
    } else if (tid == NSV + HH) {
        float a = bo[0];
        #pragma unroll
        for (int h = 0; h < HH; ++h) a += be[h] * Wo[h];
        ucS[HH] = a;
    } else if (tid >= TRB && tid < 2 * TRB) {
        // ---- phase B: track MLP, once per track, -> LDS ----
        const int t = tid - TRB;
        const float* xp = x_trk + (size_t)(b * NTRK + half * TRB + t) * 8;
        float x[8];
        *(float4*)&x[0] = *(const float4*)&xp[0];
        *(float4*)&x[4] = *(const float4*)&xp[4];
        float hb[HH];
        #pragma unroll
        for (int h = 0; h < HH; ++h) {
            float a = b1t[h];
            #pragma unroll
            for (int i = 0; i < 8; ++i) a += x[i] * W1t[i * HH + h];
            hb[h] = elu_f(a);
        }
        float sq = 0.0f;
        #pragma unroll
        for (int h2 = 0; h2 < HH; ++h2) {
            float a = b2t[h2];
            #pragma unroll
            for (int h = 0; h < HH; ++h) a += hb[h] * W2t[h * HH + h2];
            tfS[t][h2] = a;
            sq += a * a;
        }
        tfS[t][HH] = 0.5f * sq;
    }

    __syncthreads();   // rows drained to L2; proj/uc/tf staged

    // ---- read my track's tf/htsq from LDS (one-time) ----
    vf2 ntfp[8];
    float htsq;
    #pragma unroll
    for (int j = 0; j < 8; ++j) {
        vf2 t = *(const vf2*)&tfS[tl][2 * j];
        ntfp[j] = -t;
    }
    htsq = tfS[tl][HH];

    unsigned k[KK];
    #pragma unroll
    for (int q = 0; q < KK; ++q) k[q] = 0xFFFFFFFFu;

    // ---- kNN scan of this segment's 32 rows: scalar loads, depth-2 pipe ----
    const int sbase = seg * SEGN;
    const float* rp = svr + (size_t)(b * NSV + sbase) * RSTR;

    vf2 pa[8], pb[8]; float ha, hbv;

    #define LOADROW(buf, hv, idx)                                      \
        do {                                                           \
            const float* _r = rp + (size_t)(idx) * RSTR;               \
            _Pragma("unroll")                                          \
            for (int _j = 0; _j < 8; ++_j)                             \
                buf[_j] = *(const vf2*)(_r + 2 * _j);                  \
            hv = _r[HH];                                               \
        } while (0)

    #define BODY(buf, hv, idx)                                         \
        do {                                                           \
            vf2 a0 = ntfp[0] * buf[0];                                 \
            vf2 a1 = ntfp[1] * buf[1];                                 \
            vf2 a2 = ntfp[2] * buf[2];                                 \
            vf2 a3 = ntfp[3] * buf[3];                                 \
            a0 = __builtin_elementwise_fma(ntfp[4], buf[4], a0);       \
            a1 = __builtin_elementwise_fma(ntfp[5], buf[5], a1);       \
            a2 = __builtin_elementwise_fma(ntfp[6], buf[6], a2);       \
            a3 = __builtin_elementwise_fma(ntfp[7], buf[7], a3);       \
            a0 = a0 + a1; a2 = a2 + a3; a0 = a0 + a2;                  \
            float e = fmaxf((htsq + hv) + (a0.x + a0.y), 0.0f);        \
            unsigned v = (__float_as_uint(e) & 0xFFFFFF80u)            \
                         | (unsigned)(sbase + (idx));                  \
            unsigned nk0 = umin_u(v, k[0]);                            \
            unsigned nk1 = med3u(v, k[0], k[1]);                       \
            unsigned nk2 = med3u(v, k[1], k[2]);                       \
            unsigned nk3 = med3u(v, k[2], k[3]);                       \
            unsigned nk4 = med3u(v, k[3], k[4]);                       \
            unsigned nk5 = med3u(v, k[4], k[5]);                       \
            unsigned nk6 = med3u(v, k[5], k[6]);                       \
            unsigned nk7 = med3u(v, k[6], k[7]);                       \
            k[0] = nk0; k[1] = nk1; k[2] = nk2; k[3] = nk3;            \
            k[4] = nk4; k[5] = nk5; k[6] = nk6; k[7] = nk7;            \
        } while (0)

    LOADROW(pa, ha, 0);
    LOADROW(pb, hbv, 1);
    for (int s = 0; s < SEGN - 2; s += 2) {
        BODY(pa, ha, s);
        LOADROW(pa, ha, s + 2);
        BODY(pb, hbv, s + 1);
        LOADROW(pb, hbv, s + 3);
    }
    BODY(pa, ha, SEGN - 2);
    BODY(pb, hbv, SEGN - 1);

    #undef LOADROW
    #undef BODY

    // ---- segs 1..3 publish sorted lists ----
    if (seg > 0) {
        #pragma unroll
        for (int q = 0; q < KK; ++q) kbufS[tl][(seg - 1) * KK + q] = k[q];
    }
    __syncthreads();

    // ---- seg 0: exact 4-way merge, epilogue, sigmoid ----
    float local = 0.0f;
    if (tid < TRB) {
        unsigned lb[KK], lc[KK], ld[KK];
        #pragma unroll
        for (int q = 0; q < KK; ++q) {
            lb[q] = kbufS[tl][q];
            lc[q] = kbufS[tl][KK + q];
            ld[q] = kbufS[tl][2 * KK + q];
        }
        merge8(k, lb);        // k = sorted 8 smallest of seg0 u seg1
        merge8(lc, ld);       // lc = sorted 8 smallest of seg2 u seg3
        unsigned m[KK];       // final set (unsorted bitonic - set suffices)
        #pragma unroll
        for (int i = 0; i < KK; ++i) m[i] = umin_u(k[i], lc[7 - i]);

        float acc = ucS[HH];
        #pragma unroll
        for (int j = 0; j < 8; ++j) {
            acc = fmaf(-ntfp[j].x, ucS[2 * j],     acc);
            acc = fmaf(-ntfp[j].y, ucS[2 * j + 1], acc);
        }
        float mx[HH];
        #pragma unroll
        for (int h = 0; h < HH; ++h) mx[h] = -INFINITY;
        #pragma unroll
        for (int q = 0; q < KK; ++q) {
            const float* pr = &proj[m[q] & 127u][0];
            #pragma unroll
            for (int h4 = 0; h4 < 4; ++h4) {
                float4 p = *(const float4*)&pr[h4 * 4];
                mx[h4 * 4 + 0] = fmaxf(mx[h4 * 4 + 0], p.x);
                mx[h4 * 4 + 1] = fmaxf(mx[h4 * 4 + 1], p.y);
                mx[h4 * 4 + 2] = fmaxf(mx[h4 * 4 + 2], p.z);
                mx[h4 * 4 + 3] = fmaxf(mx[h4 * 4 + 3], p.w);
            }
        }
        #pragma unroll
        for (int h = 0; h < HH; ++h) acc = fmaf(mx[h], Wo[h], acc);
        local = 1.0f / (1.0f + expf(-acc));

        // wave-reduce within seg0's 4 waves
        #pragma unroll
        for (int off = 32; off > 0; off >>= 1)
            local += __shfl_down(local, off, 64);
        if ((tid & 63) == 0) sred[tid >> 6] = local;
    }
    __syncthreads();

    // ---- cross-block pooling (2 blocks per batch) ----
    if (tid == 0) {
        float part = sred[0] + sred[1] + sred[2] + sred[3];
        atomicAdd(&pool_g[b], part);
        __threadfence();
        unsigned old = atomicAdd(&cnt_g[b], 1u);
        if (old == 1u) {   // second (last) block of this batch
            float tot = atomicAdd(&pool_g[b], 0.0f);   // coherent read-back
            out[b]      = tot * (1.0f / NTRK);
            out[BB + b] = (float)b;
        }
    }
}

extern "C" void kernel_launch(void* const* d_in, const int* in_sizes, int n_in,
                              void* d_out, int out_size, void* d_ws, size_t ws_size,
                              hipStream_t stream) {
    const float* x_sv  = (const float*)d_in[0];
    const float* x_trk = (const float*)d_in[1];
    const float* W1s = (const float*)d_in[4];
    const float* b1s = (const float*)d_in[5];
    const float* W2s = (const float*)d_in[6];
    const float* b2s = (const float*)d_in[7];
    const float* W1t = (const float*)d_in[8];
    const float* b1t = (const float*)d_in[9];
    const float* W2t = (const float*)d_in[10];
    const float* b2t = (const float*)d_in[11];
    const float* We  = (const float*)d_in[12];
    const float* be  = (const float*)d_in[13];
    const float* Wo  = (const float*)d_in[14];
    const float* bo  = (const float*)d_in[15];
    float* out = (float*)d_out;

    float*    rows   = (float*)d_ws;                       // 512*128*20 f = 5.24 MB
    float*    pool_g = rows + (size_t)BB * NSV * RSTR;     // 512 f
    unsigned* cnt_g  = (unsigned*)(pool_g + BB);           // 512 u

    hipMemsetAsync(pool_g, 0, BB * (sizeof(float) + sizeof(unsigned)), stream);

    fused_all<<<BB * 2, TPB, 0, stream>>>(x_sv, x_trk,
                                          W1s, b1s, W2s, b2s,
                                          W1t, b1t, W2t, b2t,
                                          We, be, Wo, bo,
                                          rows, rows, pool_g, cnt_g, out);
}

// Round 12
// 123.928 us; speedup vs baseline: 1.2657x; 1.2657x over previous
//
#include <hip/hip_runtime.h>
#include <cmath>

#define BB   512
#define NSV  128
#define NTRK 512
#define KK   8
#define HH   16
#define TPB  1024          // threads 0-511: half 0 (+track MLP); 512-1023: half 1 (+SV MLP)
#define RSTR 20            // global row stride: [16 feats][0.5*||sv||^2][pad]
#define PSTR 20            // padded proj stride in LDS
#define TSTR 18            // tfS stride (8B-aligned for vf2 reads)

typedef float vf2 __attribute__((ext_vector_type(2)));

__device__ __forceinline__ float elu_f(float x) {
    return x > 0.0f ? x : expm1f(x);
}
__device__ __forceinline__ unsigned umin_u(unsigned a, unsigned b) { return a < b ? a : b; }
__device__ __forceinline__ unsigned med3u(unsigned a, unsigned b, unsigned c) {
    unsigned d;
    asm("v_med3_u32 %0, %1, %2, %3" : "=v"(d) : "v"(a), "v"(b), "v"(c));
    return d;
}

// One block = one batch. 1024 threads, 2-way SV-scan split per track:
// thread tid handles track (tid&511) scanning SV half (tid>>9) * 64 rows.
// Track MLP computed ONCE (threads 0-511 -> LDS). SV MLP on threads 512-639.
// Rows round-trip via global ws (scalar-load path, L2-hot). Half 1 publishes
// its sorted top-8; half 0 merges exactly and runs the epilogue alone.
__global__ __launch_bounds__(TPB, 8) void fused_all(
    const float* __restrict__ x_sv, const float* __restrict__ x_trk,
    const float* __restrict__ W1s, const float* __restrict__ b1s,
    const float* __restrict__ W2s, const float* __restrict__ b2s,
    const float* __restrict__ W1t, const float* __restrict__ b1t,
    const float* __restrict__ W2t, const float* __restrict__ b2t,
    const float* __restrict__ We,  const float* __restrict__ be,
    const float* __restrict__ Wo,  const float* __restrict__ bo,
    float* __restrict__ svw,             // ws rows, write alias
    const float* __restrict__ svr,       // ws rows, read alias (scalar loads)
    float* __restrict__ out)
{
    __shared__ float    proj[NSV][PSTR];     // 10.2 KB
    __shared__ float    tfS[NTRK][TSTR];     // 36.9 KB: tf[16], htsq
    __shared__ unsigned kbuf[NTRK][KK];      // 16.4 KB: half-1 sorted lists
    __shared__ float    ucS[HH + 1];         // u[16], c0
    __shared__ float    sred[TPB / 64];

    const int b   = blockIdx.x, tid = threadIdx.x;
    const int tl  = tid & (NTRK - 1);                             // track
    const int sh  = __builtin_amdgcn_readfirstlane(tid >> 9);     // 0/1, wave-uniform

    // ---- phase A/B in parallel across thread ranges ----
    if (tid < NTRK) {
        // track MLP, once per track -> LDS
        const float* xp = x_trk + (size_t)(b * NTRK + tid) * 8;
        float x[8];
        *(float4*)&x[0] = *(const float4*)&xp[0];
        *(float4*)&x[4] = *(const float4*)&xp[4];
        float hb[HH];
        #pragma unroll
        for (int h = 0; h < HH; ++h) {
            float a = b1t[h];
            #pragma unroll
            for (int i = 0; i < 8; ++i) a += x[i] * W1t[i * HH + h];
            hb[h] = elu_f(a);
        }
        float sq = 0.0f;
        #pragma unroll
        for (int h2 = 0; h2 < HH; ++h2) {
            float a = b2t[h2];
            #pragma unroll
            for (int h = 0; h < HH; ++h) a += hb[h] * W2t[h * HH + h2];
            tfS[tid][h2] = a;
            sq += a * a;
        }
        tfS[tid][HH] = 0.5f * sq;
    } else if (tid < NTRK + NSV) {
        // SV MLP -> global rows + LDS proj
        const int s = tid - NTRK;
        const float* xp = x_sv + (size_t)(b * NSV + s) * 2;
        float x0 = xp[0], x1 = xp[1];
        float hb[HH];
        #pragma unroll
        for (int h = 0; h < HH; ++h)
            hb[h] = elu_f(x0 * W1s[h] + x1 * W1s[HH + h] + b1s[h]);
        float o[HH], sq = 0.0f;
        #pragma unroll
        for (int h2 = 0; h2 < HH; ++h2) {
            float a = b2s[h2];
            #pragma unroll
            for (int h = 0; h < HH; ++h) a += hb[h] * W2s[h * HH + h2];
            o[h2] = a;
            sq += a * a;
        }
        float* dst = svw + (size_t)(b * NSV + s) * RSTR;
        #pragma unroll
        for (int h4 = 0; h4 < 4; ++h4)
            *(float4*)&dst[h4 * 4] = make_float4(o[h4*4], o[h4*4+1], o[h4*4+2], o[h4*4+3]);
        dst[HH] = 0.5f * sq;
        #pragma unroll
        for (int h = 0; h < HH; ++h) {
            float a = 0.0f;
            #pragma unroll
            for (int j = 0; j < HH; ++j) a += o[j] * We[(HH + j) * HH + h];
            proj[s][h] = a;
        }
    } else if (tid < NTRK + NSV + HH) {
        int j = tid - NTRK - NSV;
        float a = 0.0f;
        #pragma unroll
        for (int h = 0; h < HH; ++h)
            a += (We[j * HH + h] - We[(HH + j) * HH + h]) * Wo[h];
        ucS[j] = a;
    } else if (tid == NTRK + NSV + HH) {
        float a = bo[0];
        #pragma unroll
        for (int h = 0; h < HH; ++h) a += be[h] * Wo[h];
        ucS[HH] = a;
    }

    __syncthreads();   // rows drained to L2; proj/uc/tf staged

    // ---- read my track's tf/htsq from LDS (one-time) ----
    vf2 ntfp[8];
    float htsq;
    #pragma unroll
    for (int j = 0; j < 8; ++j) {
        vf2 t = *(const vf2*)&tfS[tl][2 * j];
        ntfp[j] = -t;
    }
    htsq = tfS[tl][HH];

    unsigned k[KK];
    #pragma unroll
    for (int q = 0; q < KK; ++q) k[q] = 0xFFFFFFFFu;

    // ---- kNN scan of this half's 64 rows: scalar loads, depth-3 pipeline ----
    const int sbase = sh * 64;
    const float* rp = svr + (size_t)(b * NSV + sbase) * RSTR;

    vf2 p0[8], p1[8], p2[8]; float h0, h1, h2;

    #define LOADROW(buf, hv, idx)                                      \
        do {                                                           \
            const float* _r = rp + (size_t)(idx) * RSTR;               \
            _Pragma("unroll")                                          \
            for (int _j = 0; _j < 8; ++_j)                             \
                buf[_j] = *(const vf2*)(_r + 2 * _j);                  \
            hv = _r[HH];                                               \
        } while (0)

    #define BODY(buf, hv, idx)                                         \
        do {                                                           \
            vf2 a0 = ntfp[0] * buf[0];                                 \
            vf2 a1 = ntfp[1] * buf[1];                                 \
            vf2 a2 = ntfp[2] * buf[2];                                 \
            vf2 a3 = ntfp[3] * buf[3];                                 \
            a0 = __builtin_elementwise_fma(ntfp[4], buf[4], a0);       \
            a1 = __builtin_elementwise_fma(ntfp[5], buf[5], a1);       \
            a2 = __builtin_elementwise_fma(ntfp[6], buf[6], a2);       \
            a3 = __builtin_elementwise_fma(ntfp[7], buf[7], a3);       \
            a0 = a0 + a1; a2 = a2 + a3; a0 = a0 + a2;                  \
            float e = fmaxf((htsq + hv) + (a0.x + a0.y), 0.0f);        \
            unsigned v = (__float_as_uint(e) & 0xFFFFFF80u)            \
                         | (unsigned)(sbase + (idx));                  \
            unsigned nk0 = umin_u(v, k[0]);                            \
            unsigned nk1 = med3u(v, k[0], k[1]);                       \
            unsigned nk2 = med3u(v, k[1], k[2]);                       \
            unsigned nk3 = med3u(v, k[2], k[3]);                       \
            unsigned nk4 = med3u(v, k[3], k[4]);                       \
            unsigned nk5 = med3u(v, k[4], k[5]);                       \
            unsigned nk6 = med3u(v, k[5], k[6]);                       \
            unsigned nk7 = med3u(v, k[6], k[7]);                       \
            k[0] = nk0; k[1] = nk1; k[2] = nk2; k[3] = nk3;            \
            k[4] = nk4; k[5] = nk5; k[6] = nk6; k[7] = nk7;            \
        } while (0)

    LOADROW(p0, h0, 0);
    LOADROW(p1, h1, 1);
    LOADROW(p2, h2, 2);
    for (int s = 0; s < 60; s += 3) {
        BODY(p0, h0, s);     LOADROW(p0, h0, s + 3);
        BODY(p1, h1, s + 1); LOADROW(p1, h1, s + 4);
        BODY(p2, h2, s + 2); LOADROW(p2, h2, s + 5);
    }
    BODY(p0, h0, 60); LOADROW(p0, h0, 63);
    BODY(p1, h1, 61);
    BODY(p2, h2, 62);
    BODY(p0, h0, 63);

    #undef LOADROW
    #undef BODY

    // ---- half 1 publishes its sorted list; half 0 merges + epilogue ----
    if (sh == 1) {
        #pragma unroll
        for (int q = 0; q < KK; ++q) kbuf[tl][q] = k[q];
    }
    __syncthreads();

    float local = 0.0f;
    if (sh == 0) {
        unsigned m[KK];    // exact 8-smallest of union (bitonic set, unsorted)
        #pragma unroll
        for (int i = 0; i < KK; ++i) m[i] = umin_u(k[i], kbuf[tl][7 - i]);

        float acc = ucS[HH];
        #pragma unroll
        for (int j = 0; j < 8; ++j) {
            acc = fmaf(-ntfp[j].x, ucS[2 * j],     acc);
            acc = fmaf(-ntfp[j].y, ucS[2 * j + 1], acc);
        }
        float mx[HH];
        #pragma unroll
        for (int h = 0; h < HH; ++h) mx[h] = -INFINITY;
        #pragma unroll
        for (int q = 0; q < KK; ++q) {
            const float* pr = &proj[m[q] & 127u][0];
            #pragma unroll
            for (int h4 = 0; h4 < 4; ++h4) {
                float4 p = *(const float4*)&pr[h4 * 4];
                mx[h4 * 4 + 0] = fmaxf(mx[h4 * 4 + 0], p.x);
                mx[h4 * 4 + 1] = fmaxf(mx[h4 * 4 + 1], p.y);
                mx[h4 * 4 + 2] = fmaxf(mx[h4 * 4 + 2], p.z);
                mx[h4 * 4 + 3] = fmaxf(mx[h4 * 4 + 3], p.w);
            }
        }
        #pragma unroll
        for (int h = 0; h < HH; ++h) acc = fmaf(mx[h], Wo[h], acc);
        local = 1.0f / (1.0f + expf(-acc));
    }

    // ---- block mean-pool (half 1 contributes zeros) ----
    #pragma unroll
    for (int off = 32; off > 0; off >>= 1)
        local += __shfl_down(local, off, 64);
    if ((tid & 63) == 0) sred[tid >> 6] = local;
    __syncthreads();
    if (tid == 0) {
        float tot = 0.0f;
        #pragma unroll
        for (int w = 0; w < TPB / 64; ++w) tot += sred[w];
        out[b]      = tot * (1.0f / NTRK);
        out[BB + b] = (float)b;
    }
}

extern "C" void kernel_launch(void* const* d_in, const int* in_sizes, int n_in,
                              void* d_out, int out_size, void* d_ws, size_t ws_size,
                              hipStream_t stream) {
    const float* x_sv  = (const float*)d_in[0];
    const float* x_trk = (const float*)d_in[1];
    const float* W1s = (const float*)d_in[4];
    const float* b1s = (const float*)d_in[5];
    const float* W2s = (const float*)d_in[6];
    const float* b2s = (const float*)d_in[7];
    const float* W1t = (const float*)d_in[8];
    const float* b1t = (const float*)d_in[9];
    const float* W2t = (const float*)d_in[10];
    const float* b2t = (const float*)d_in[11];
    const float* We  = (const float*)d_in[12];
    const float* be  = (const float*)d_in[13];
    const float* Wo  = (const float*)d_in[14];
    const float* bo  = (const float*)d_in[15];
    float* out = (float*)d_out;

    float* rows = (float*)d_ws;      // 512*128*20 floats = 5.24 MB

    fused_all<<<BB, TPB, 0, stream>>>(x_sv, x_trk,
                                      W1s, b1s, W2s, b2s,
                                      W1t, b1t, W2t, b2t,
                                      We, be, Wo, bo,
                                      rows, rows, out);
}